// Round 1
// baseline (195.258 us; speedup 1.0000x reference)
//
#include <hip/hip_runtime.h>
#include <stdint.h>

typedef _Float16 f16x8 __attribute__((ext_vector_type(8)));
typedef float f32x4 __attribute__((ext_vector_type(4)));

#define LOG2E 1.44269504088896340736f
#define NEGINF (-1e16f)

constexpr int kN = 4096;   // nodes
constexpr int kD = 64;     // feature dim
constexpr int kB = 8;      // batch

// ---------------------------------------------------------------------------
// Kernel 1: h[row][d] = sum_c x[row][c] * W[d][c]   (f32 math, f16 store)
// 512 blocks x 256 thr; block handles 64 rows; thread: 1 row x 16 d-outputs
// ---------------------------------------------------------------------------
__global__ __launch_bounds__(256) void hproj_kernel(const float* __restrict__ x,
                                                    const float* __restrict__ W,
                                                    _Float16* __restrict__ hout)
{
    __shared__ float Wt[64][64];   // Wt[c][d] = W[d][c]
    __shared__ float xs[64][65];   // +1 pad to break bank stride

    const int tid = threadIdx.x;
    const int r   = tid >> 2;          // 0..63
    const int c0  = (tid & 3) * 16;    // 0,16,32,48

    // stage W transposed
    #pragma unroll
    for (int j = 0; j < 16; j += 4) {
        const float4 v = *(const float4*)(W + r * 64 + c0 + j);
        Wt[c0 + j + 0][r] = v.x;
        Wt[c0 + j + 1][r] = v.y;
        Wt[c0 + j + 2][r] = v.z;
        Wt[c0 + j + 3][r] = v.w;
    }
    const long rowbase = (long)blockIdx.x * 64;
    #pragma unroll
    for (int j = 0; j < 16; j += 4) {
        const float4 v = *(const float4*)(x + (rowbase + r) * 64 + c0 + j);
        xs[r][c0 + j + 0] = v.x;
        xs[r][c0 + j + 1] = v.y;
        xs[r][c0 + j + 2] = v.z;
        xs[r][c0 + j + 3] = v.w;
    }
    __syncthreads();

    const int d0 = (tid & 3) * 16;
    f32x4 acc[4] = {{0.f,0.f,0.f,0.f},{0.f,0.f,0.f,0.f},{0.f,0.f,0.f,0.f},{0.f,0.f,0.f,0.f}};
    #pragma unroll 4
    for (int c = 0; c < 64; ++c) {
        const float xv = xs[r][c];
        const f32x4* wrow = (const f32x4*)&Wt[c][d0];
        #pragma unroll
        for (int k = 0; k < 4; ++k) acc[k] += wrow[k] * xv;
    }
    f16x8 o0, o1;
    #pragma unroll
    for (int j = 0; j < 8; ++j) {
        o0[j] = (_Float16)acc[j >> 2][j & 3];
        o1[j] = (_Float16)acc[2 + (j >> 2)][j & 3];
    }
    *(f16x8*)(hout + (rowbase + r) * 64 + d0)     = o0;
    *(f16x8*)(hout + (rowbase + r) * 64 + d0 + 8) = o1;
}

// ---------------------------------------------------------------------------
// Kernel 2: bit-pack graph (int32 0/1, [4096][4096]) -> uint32 [4096][128]
// ---------------------------------------------------------------------------
__global__ __launch_bounds__(256) void bitpack_kernel(const int* __restrict__ g,
                                                      uint32_t* __restrict__ mw)
{
    const long w = (long)blockIdx.x * 256 + threadIdx.x;  // word index
    const int4* p = (const int4*)(g + w * 32);
    uint32_t bits = 0;
    #pragma unroll
    for (int j = 0; j < 8; ++j) {
        const int4 v = p[j];
        bits |= (uint32_t)(v.x != 0) << (j * 4 + 0);
        bits |= (uint32_t)(v.y != 0) << (j * 4 + 1);
        bits |= (uint32_t)(v.z != 0) << (j * 4 + 2);
        bits |= (uint32_t)(v.w != 0) << (j * 4 + 3);
    }
    mw[w] = bits;
}

// ---------------------------------------------------------------------------
// Kernel 3: flash attention.  grid (64, 8), 256 thr (4 waves).
// Block: 64 Q rows (16/wave); loop KV tiles of 64.
// LDS: K [64 rows][128B] swizzled, V^T [64 d][128B] swizzled, P per-wave.
// ---------------------------------------------------------------------------
__global__ __launch_bounds__(256) void attn_kernel(const _Float16* __restrict__ h,
                                                   const uint32_t* __restrict__ mw,
                                                   const float* __restrict__ bias,
                                                   float* __restrict__ out)
{
    __shared__ alignas(16) char Kl[64 * 128];
    __shared__ alignas(16) char Vt[64 * 128];
    __shared__ alignas(16) char Pl[4][16 * 128];

    const int b    = blockIdx.y;
    const int q0   = blockIdx.x * 64;
    const int tid  = threadIdx.x;
    const int wave = tid >> 6;
    const int lane = tid & 63;
    const int lg   = lane >> 4;   // 0..3
    const int ll   = lane & 15;   // 0..15

    const _Float16* hb = h + (long)b * kN * kD;

    // Q fragments (A-frag: row = ll, k = 8*lg + e), resident for whole kernel
    const int qrow = q0 + wave * 16 + ll;
    const f16x8 qf0 = *(const f16x8*)(hb + qrow * 64 + lg * 8);
    const f16x8 qf1 = *(const f16x8*)(hb + qrow * 64 + 32 + lg * 8);

    f32x4 Oacc[4] = {{0.f,0.f,0.f,0.f},{0.f,0.f,0.f,0.f},{0.f,0.f,0.f,0.f},{0.f,0.f,0.f,0.f}};
    float m_run[4], l_run[4];
    #pragma unroll
    for (int r = 0; r < 4; ++r) { m_run[r] = NEGINF; l_run[r] = 0.f; }

    const int sr = tid >> 2;          // staging row 0..63
    const int sc = (tid & 3) * 16;    // staging col group

    for (int kv0 = 0; kv0 < kN; kv0 += 64) {
        __syncthreads();   // previous iteration done reading LDS
        {
            const _Float16* src = hb + (long)(kv0 + sr) * 64 + sc;
            const f16x8 v0 = *(const f16x8*)(src);
            const f16x8 v1 = *(const f16x8*)(src + 8);
            const int swzK = (sr & 7) << 4;
            *(f16x8*)(Kl + sr * 128 + ((sc * 2)      ^ swzK)) = v0;
            *(f16x8*)(Kl + sr * 128 + ((sc * 2 + 16) ^ swzK)) = v1;
            #pragma unroll
            for (int j = 0; j < 8; ++j) {
                const int d1 = sc + j;
                const int d2 = sc + 8 + j;
                *(_Float16*)(Vt + d1 * 128 + ((sr * 2) ^ ((d1 & 7) << 4))) = v0[j];
                *(_Float16*)(Vt + d2 * 128 + ((sr * 2) ^ ((d2 & 7) << 4))) = v1[j];
            }
        }
        __syncthreads();   // staging visible

        // ---- S = Q K^T : four 16x16 tiles along kv ----
        f32x4 S[4];
        #pragma unroll
        for (int t = 0; t < 4; ++t) {
            const int krow = t * 16 + ll;
            const char* kb = Kl + krow * 128;
            const int swz = (krow & 7) << 4;
            const f16x8 k0 = *(const f16x8*)(kb + ((lg * 16)      ^ swz));
            const f16x8 k1 = *(const f16x8*)(kb + ((64 + lg * 16) ^ swz));
            f32x4 s = {0.f, 0.f, 0.f, 0.f};
            s = __builtin_amdgcn_mfma_f32_16x16x32_f16(qf0, k0, s, 0, 0, 0);
            s = __builtin_amdgcn_mfma_f32_16x16x32_f16(qf1, k1, s, 0, 0, 0);
            S[t] = s;
        }

        // ---- mask + online softmax (C/D layout: row = 4*lg + r, col = 16*t + ll) ----
        const int wbase = kv0 >> 5;
        float scale[4];
        #pragma unroll
        for (int r = 0; r < 4; ++r) {
            const int row = q0 + wave * 16 + lg * 4 + r;
            const uint32_t w0 = mw[row * 128 + wbase];
            const uint32_t w1 = mw[row * 128 + wbase + 1];
            float mloc = NEGINF;
            #pragma unroll
            for (int t = 0; t < 4; ++t) {
                const int kv = t * 16 + ll;            // 0..63
                const uint32_t wv = (kv < 32) ? w0 : w1;
                const float sv = ((wv >> (kv & 31)) & 1u) ? S[t][r] : NEGINF;
                S[t][r] = sv;
                mloc = fmaxf(mloc, sv);
            }
            mloc = fmaxf(mloc, __shfl_xor(mloc, 1));
            mloc = fmaxf(mloc, __shfl_xor(mloc, 2));
            mloc = fmaxf(mloc, __shfl_xor(mloc, 4));
            mloc = fmaxf(mloc, __shfl_xor(mloc, 8));
            const float mnew = fmaxf(m_run[r], mloc);
            const float sc_  = exp2f((m_run[r] - mnew) * LOG2E);
            m_run[r] = mnew;
            scale[r] = sc_;
            float ps = 0.f;
            #pragma unroll
            for (int t = 0; t < 4; ++t) {
                const float p = exp2f((S[t][r] - mnew) * LOG2E);
                S[t][r] = p;
                ps += p;
            }
            ps += __shfl_xor(ps, 1);
            ps += __shfl_xor(ps, 2);
            ps += __shfl_xor(ps, 4);
            ps += __shfl_xor(ps, 8);
            l_run[r] = l_run[r] * sc_ + ps;
        }
        #pragma unroll
        for (int dt = 0; dt < 4; ++dt)
            #pragma unroll
            for (int r = 0; r < 4; ++r)
                Oacc[dt][r] *= scale[r];

        // ---- P -> LDS (f16, per-wave buffer, same swizzle) ----
        char* pw = Pl[wave];
        #pragma unroll
        for (int r = 0; r < 4; ++r) {
            const int prow = lg * 4 + r;
            const int swz = (prow & 7) << 4;
            #pragma unroll
            for (int t = 0; t < 4; ++t) {
                const int kv = t * 16 + ll;
                *(_Float16*)(pw + prow * 128 + ((kv * 2) ^ swz)) = (_Float16)S[t][r];
            }
        }
        __syncthreads();   // P visible (also keeps waves in lockstep)

        // ---- O += P V  (A = P rows=ll, k over kv; B = V^T rows = d) ----
        const char* pr = Pl[wave] + ll * 128;
        const int swzp = (ll & 7) << 4;
        const f16x8 p0 = *(const f16x8*)(pr + ((lg * 16)      ^ swzp));
        const f16x8 p1 = *(const f16x8*)(pr + ((64 + lg * 16) ^ swzp));
        #pragma unroll
        for (int dt = 0; dt < 4; ++dt) {
            const int vrow = dt * 16 + ll;
            const char* vb = Vt + vrow * 128;
            const int swz = (vrow & 7) << 4;
            const f16x8 v0 = *(const f16x8*)(vb + ((lg * 16)      ^ swz));
            const f16x8 v1 = *(const f16x8*)(vb + ((64 + lg * 16) ^ swz));
            Oacc[dt] = __builtin_amdgcn_mfma_f32_16x16x32_f16(p0, v0, Oacc[dt], 0, 0, 0);
            Oacc[dt] = __builtin_amdgcn_mfma_f32_16x16x32_f16(p1, v1, Oacc[dt], 0, 0, 0);
        }
    }

    // ---- epilogue: normalize, add bias, store ----
    float inv[4];
    #pragma unroll
    for (int r = 0; r < 4; ++r) inv[r] = 1.0f / l_run[r];
    #pragma unroll
    for (int dt = 0; dt < 4; ++dt) {
        const int col = dt * 16 + ll;
        const float bv = bias[col];
        #pragma unroll
        for (int r = 0; r < 4; ++r) {
            const long row = q0 + wave * 16 + lg * 4 + r;
            out[((long)b * kN + row) * 64 + col] = Oacc[dt][r] * inv[r] + bv;
        }
    }
}

// ---------------------------------------------------------------------------
extern "C" void kernel_launch(void* const* d_in, const int* in_sizes, int n_in,
                              void* d_out, int out_size, void* d_ws, size_t ws_size,
                              hipStream_t stream) {
    const float*  x     = (const float*)d_in[0];   // [8,4096,64]
    const int*    graph = (const int*)d_in[1];     // [4096,4096]
    const float*  W     = (const float*)d_in[2];   // [64,64]
    const float*  bias  = (const float*)d_in[3];   // [64]
    float*        outp  = (float*)d_out;

    _Float16* hptr  = (_Float16*)d_ws;                          // 4 MiB
    uint32_t* mwptr = (uint32_t*)((char*)d_ws + (4u << 20));    // 2 MiB

    hproj_kernel<<<dim3(kB * kN / 64), dim3(256), 0, stream>>>(x, W, hptr);
    bitpack_kernel<<<dim3(kN * (kN / 32) / 256), dim3(256), 0, stream>>>(graph, mwptr);
    attn_kernel<<<dim3(kN / 64, kB), dim3(256), 0, stream>>>(hptr, mwptr, bias, outp);
}

// Round 2
// 166.577 us; speedup vs baseline: 1.1722x; 1.1722x over previous
//
#include <hip/hip_runtime.h>
#include <stdint.h>

typedef _Float16 f16x8 __attribute__((ext_vector_type(8)));
typedef float f32x4 __attribute__((ext_vector_type(4)));

#define LOG2E 1.44269504088896340736f
#define NEGINF (-1e16f)

constexpr int kN = 4096;   // nodes
constexpr int kD = 64;     // feature dim
constexpr int kB = 8;      // batch

// ---------------------------------------------------------------------------
// Kernel 1: h[row][d] = sum_c x[row][c] * W[d][c]   (f32 math, f16 store)
// ---------------------------------------------------------------------------
__global__ __launch_bounds__(256) void hproj_kernel(const float* __restrict__ x,
                                                    const float* __restrict__ W,
                                                    _Float16* __restrict__ hout)
{
    __shared__ float Wt[64][64];   // Wt[c][d] = W[d][c]
    __shared__ float xs[64][65];

    const int tid = threadIdx.x;
    const int r   = tid >> 2;          // 0..63
    const int c0  = (tid & 3) * 16;    // 0,16,32,48

    #pragma unroll
    for (int j = 0; j < 16; j += 4) {
        const float4 v = *(const float4*)(W + r * 64 + c0 + j);
        Wt[c0 + j + 0][r] = v.x;
        Wt[c0 + j + 1][r] = v.y;
        Wt[c0 + j + 2][r] = v.z;
        Wt[c0 + j + 3][r] = v.w;
    }
    const long rowbase = (long)blockIdx.x * 64;
    #pragma unroll
    for (int j = 0; j < 16; j += 4) {
        const float4 v = *(const float4*)(x + (rowbase + r) * 64 + c0 + j);
        xs[r][c0 + j + 0] = v.x;
        xs[r][c0 + j + 1] = v.y;
        xs[r][c0 + j + 2] = v.z;
        xs[r][c0 + j + 3] = v.w;
    }
    __syncthreads();

    const int d0 = (tid & 3) * 16;
    f32x4 acc[4] = {{0.f,0.f,0.f,0.f},{0.f,0.f,0.f,0.f},{0.f,0.f,0.f,0.f},{0.f,0.f,0.f,0.f}};
    #pragma unroll 4
    for (int c = 0; c < 64; ++c) {
        const float xv = xs[r][c];
        const f32x4* wrow = (const f32x4*)&Wt[c][d0];
        #pragma unroll
        for (int k = 0; k < 4; ++k) acc[k] += wrow[k] * xv;
    }
    f16x8 o0, o1;
    #pragma unroll
    for (int j = 0; j < 8; ++j) {
        o0[j] = (_Float16)acc[j >> 2][j & 3];
        o1[j] = (_Float16)acc[2 + (j >> 2)][j & 3];
    }
    *(f16x8*)(hout + (rowbase + r) * 64 + d0)     = o0;
    *(f16x8*)(hout + (rowbase + r) * 64 + d0 + 8) = o1;
}

// ---------------------------------------------------------------------------
// Kernel 2: bit-pack graph (int32 0/1, [4096][4096]) -> uint32 [4096][128]
// ---------------------------------------------------------------------------
__global__ __launch_bounds__(256) void bitpack_kernel(const int* __restrict__ g,
                                                      uint32_t* __restrict__ mw)
{
    const long w = (long)blockIdx.x * 256 + threadIdx.x;  // word index
    const int4* p = (const int4*)(g + w * 32);
    uint32_t bits = 0;
    #pragma unroll
    for (int j = 0; j < 8; ++j) {
        const int4 v = p[j];
        bits |= (uint32_t)(v.x != 0) << (j * 4 + 0);
        bits |= (uint32_t)(v.y != 0) << (j * 4 + 1);
        bits |= (uint32_t)(v.z != 0) << (j * 4 + 2);
        bits |= (uint32_t)(v.w != 0) << (j * 4 + 3);
    }
    mw[w] = bits;
}

// ---------------------------------------------------------------------------
// Kernel 3: flash attention over a KV chunk.  grid (64, 8, KS), 256 thr.
// Block: 64 Q rows (16/wave); loop KV tiles of 64 within [split*kvlen, ...).
// Double-buffered K/Vt staging, reg-prefetch, 1 barrier/iter.
// If outp != null (KS==1): write normalized+bias. Else write partials.
// ---------------------------------------------------------------------------
__global__ __launch_bounds__(256) void attn_kernel(const _Float16* __restrict__ h,
                                                   const uint32_t* __restrict__ mw,
                                                   const float* __restrict__ bias,
                                                   float* __restrict__ outp,
                                                   float* __restrict__ pO,
                                                   float* __restrict__ pml,
                                                   int kvlen)
{
    __shared__ alignas(16) char Kl[2][64 * 128];
    __shared__ alignas(16) char Vt[2][64 * 128];
    __shared__ alignas(16) char Pl[4][16 * 128];

    const int b     = blockIdx.y;
    const int split = blockIdx.z;
    const int q0    = blockIdx.x * 64;
    const int tid   = threadIdx.x;
    const int wave  = tid >> 6;
    const int lane  = tid & 63;
    const int lg    = lane >> 4;   // 0..3
    const int ll    = lane & 15;   // 0..15

    const _Float16* hb = h + (long)b * kN * kD;
    const int kv_base  = split * kvlen;
    const int NT       = kvlen / 64;

    // Q fragments (A-frag: row = ll, k = 8*lg + e), resident for whole kernel
    const int qrow = q0 + wave * 16 + ll;
    const f16x8 qf0 = *(const f16x8*)(hb + qrow * 64 + lg * 8);
    const f16x8 qf1 = *(const f16x8*)(hb + qrow * 64 + 32 + lg * 8);

    f32x4 Oacc[4] = {{0.f,0.f,0.f,0.f},{0.f,0.f,0.f,0.f},{0.f,0.f,0.f,0.f},{0.f,0.f,0.f,0.f}};
    float m_run[4], l_run[4];
    #pragma unroll
    for (int r = 0; r < 4; ++r) { m_run[r] = NEGINF; l_run[r] = 0.f; }

    const int sr = tid >> 2;          // staging row 0..63
    const int sc = (tid & 3) * 16;    // staging col group

    // stage tile 0
    {
        const _Float16* src = hb + (long)(kv_base + sr) * 64 + sc;
        const f16x8 v0 = *(const f16x8*)(src);
        const f16x8 v1 = *(const f16x8*)(src + 8);
        const int swzK = (sr & 7) << 4;
        *(f16x8*)(Kl[0] + sr * 128 + ((sc * 2)      ^ swzK)) = v0;
        *(f16x8*)(Kl[0] + sr * 128 + ((sc * 2 + 16) ^ swzK)) = v1;
        #pragma unroll
        for (int j = 0; j < 8; ++j) {
            const int d1 = sc + j;
            const int d2 = sc + 8 + j;
            *(_Float16*)(Vt[0] + d1 * 128 + ((sr * 2) ^ ((d1 & 7) << 4))) = v0[j];
            *(_Float16*)(Vt[0] + d2 * 128 + ((sr * 2) ^ ((d2 & 7) << 4))) = v1[j];
        }
    }

    int cur = 0;
    for (int it = 0; it < NT; ++it) {
        const int kv0 = kv_base + it * 64;

        // ---- early-issue next tile's global loads (T14) ----
        f16x8 nv0{}, nv1{};
        if (it + 1 < NT) {
            const _Float16* src = hb + (long)(kv0 + 64 + sr) * 64 + sc;
            nv0 = *(const f16x8*)(src);
            nv1 = *(const f16x8*)(src + 8);
        }
        // early-issue mask words for this tile (uint2, 8B aligned)
        const int wbase = kv0 >> 5;
        uint2 mrow[4];
        #pragma unroll
        for (int r = 0; r < 4; ++r) {
            const int row = q0 + wave * 16 + lg * 4 + r;
            mrow[r] = *(const uint2*)(mw + row * 128 + wbase);
        }

        __syncthreads();   // staging of buf[cur] visible; buf[cur^1] free to write

        // ---- S = Q K^T : four 16x16 tiles along kv ----
        f32x4 S[4];
        #pragma unroll
        for (int t = 0; t < 4; ++t) {
            const int krow = t * 16 + ll;
            const char* kb = Kl[cur] + krow * 128;
            const int swz = (krow & 7) << 4;
            const f16x8 k0 = *(const f16x8*)(kb + ((lg * 16)      ^ swz));
            const f16x8 k1 = *(const f16x8*)(kb + ((64 + lg * 16) ^ swz));
            f32x4 s = {0.f, 0.f, 0.f, 0.f};
            s = __builtin_amdgcn_mfma_f32_16x16x32_f16(qf0, k0, s, 0, 0, 0);
            s = __builtin_amdgcn_mfma_f32_16x16x32_f16(qf1, k1, s, 0, 0, 0);
            S[t] = s;
        }

        // ---- mask + online softmax (C/D: row = 4*lg + r, col = 16*t + ll) ----
        float scale[4];
        #pragma unroll
        for (int r = 0; r < 4; ++r) {
            const uint32_t w0 = mrow[r].x;
            const uint32_t w1 = mrow[r].y;
            float mloc = NEGINF;
            #pragma unroll
            for (int t = 0; t < 4; ++t) {
                const int kv = t * 16 + ll;            // 0..63
                const uint32_t wv = (kv < 32) ? w0 : w1;
                const float sv = ((wv >> (kv & 31)) & 1u) ? S[t][r] : NEGINF;
                S[t][r] = sv;
                mloc = fmaxf(mloc, sv);
            }
            mloc = fmaxf(mloc, __shfl_xor(mloc, 1));
            mloc = fmaxf(mloc, __shfl_xor(mloc, 2));
            mloc = fmaxf(mloc, __shfl_xor(mloc, 4));
            mloc = fmaxf(mloc, __shfl_xor(mloc, 8));
            const float mnew = fmaxf(m_run[r], mloc);
            const float sc_  = exp2f((m_run[r] - mnew) * LOG2E);
            m_run[r] = mnew;
            scale[r] = sc_;
            float ps = 0.f;
            #pragma unroll
            for (int t = 0; t < 4; ++t) {
                const float p = exp2f((S[t][r] - mnew) * LOG2E);
                S[t][r] = p;
                ps += p;
            }
            ps += __shfl_xor(ps, 1);
            ps += __shfl_xor(ps, 2);
            ps += __shfl_xor(ps, 4);
            ps += __shfl_xor(ps, 8);
            l_run[r] = l_run[r] * sc_ + ps;
        }
        #pragma unroll
        for (int dt = 0; dt < 4; ++dt)
            #pragma unroll
            for (int r = 0; r < 4; ++r)
                Oacc[dt][r] *= scale[r];

        // ---- P -> per-wave LDS (wave-coherent: no barrier needed) ----
        char* pw = Pl[wave];
        #pragma unroll
        for (int r = 0; r < 4; ++r) {
            const int prow = lg * 4 + r;
            const int swz = (prow & 7) << 4;
            #pragma unroll
            for (int t = 0; t < 4; ++t) {
                const int kv = t * 16 + ll;
                *(_Float16*)(pw + prow * 128 + ((kv * 2) ^ swz)) = (_Float16)S[t][r];
            }
        }

        // ---- O += P V ----
        const char* pr = Pl[wave] + ll * 128;
        const int swzp = (ll & 7) << 4;
        const f16x8 p0 = *(const f16x8*)(pr + ((lg * 16)      ^ swzp));
        const f16x8 p1 = *(const f16x8*)(pr + ((64 + lg * 16) ^ swzp));
        #pragma unroll
        for (int dt = 0; dt < 4; ++dt) {
            const int vrow = dt * 16 + ll;
            const char* vb = Vt[cur] + vrow * 128;
            const int swz = (vrow & 7) << 4;
            const f16x8 v0 = *(const f16x8*)(vb + ((lg * 16)      ^ swz));
            const f16x8 v1 = *(const f16x8*)(vb + ((64 + lg * 16) ^ swz));
            Oacc[dt] = __builtin_amdgcn_mfma_f32_16x16x32_f16(p0, v0, Oacc[dt], 0, 0, 0);
            Oacc[dt] = __builtin_amdgcn_mfma_f32_16x16x32_f16(p1, v1, Oacc[dt], 0, 0, 0);
        }

        // ---- write prefetched tile into the other buffer ----
        if (it + 1 < NT) {
            const int nb = cur ^ 1;
            const int swzK = (sr & 7) << 4;
            *(f16x8*)(Kl[nb] + sr * 128 + ((sc * 2)      ^ swzK)) = nv0;
            *(f16x8*)(Kl[nb] + sr * 128 + ((sc * 2 + 16) ^ swzK)) = nv1;
            #pragma unroll
            for (int j = 0; j < 8; ++j) {
                const int d1 = sc + j;
                const int d2 = sc + 8 + j;
                *(_Float16*)(Vt[nb] + d1 * 128 + ((sr * 2) ^ ((d1 & 7) << 4))) = nv0[j];
                *(_Float16*)(Vt[nb] + d2 * 128 + ((sr * 2) ^ ((d2 & 7) << 4))) = nv1[j];
            }
        }
        cur ^= 1;
    }

    // ---- epilogue ----
    if (outp != nullptr) {
        float inv[4];
        #pragma unroll
        for (int r = 0; r < 4; ++r) inv[r] = 1.0f / l_run[r];
        #pragma unroll
        for (int dt = 0; dt < 4; ++dt) {
            const int col = dt * 16 + ll;
            const float bv = bias[col];
            #pragma unroll
            for (int r = 0; r < 4; ++r) {
                const long row = q0 + wave * 16 + lg * 4 + r;
                outp[((long)b * kN + row) * 64 + col] = Oacc[dt][r] * inv[r] + bv;
            }
        }
    } else {
        const long sb = (long)split * kB * kN + (long)b * kN;
        #pragma unroll
        for (int dt = 0; dt < 4; ++dt) {
            const int col = dt * 16 + ll;
            #pragma unroll
            for (int r = 0; r < 4; ++r) {
                const long row = q0 + wave * 16 + lg * 4 + r;
                pO[(sb + row) * 64 + col] = Oacc[dt][r];
            }
        }
        if (ll == 0) {
            #pragma unroll
            for (int r = 0; r < 4; ++r) {
                const long row = q0 + wave * 16 + lg * 4 + r;
                pml[(sb + row) * 2 + 0] = m_run[r];
                pml[(sb + row) * 2 + 1] = l_run[r];
            }
        }
    }
}

// ---------------------------------------------------------------------------
// Kernel 4: combine split-KV partials.  idx -> (row = b*N+q, d4)
// ---------------------------------------------------------------------------
__global__ __launch_bounds__(256) void combine_kernel(const float* __restrict__ pO,
                                                      const float* __restrict__ pml,
                                                      const float* __restrict__ bias,
                                                      float* __restrict__ outp,
                                                      int ks)
{
    const long idx = (long)blockIdx.x * 256 + threadIdx.x;  // B*N*16 groups
    const long row = idx >> 4;
    const int  d4  = (int)(idx & 15) * 4;

    float M = NEGINF;
    for (int s = 0; s < ks; ++s)
        M = fmaxf(M, pml[((long)s * kB * kN + row) * 2]);

    float L = 0.f;
    f32x4 acc = {0.f, 0.f, 0.f, 0.f};
    for (int s = 0; s < ks; ++s) {
        const long srow = (long)s * kB * kN + row;
        const float m = pml[srow * 2 + 0];
        const float l = pml[srow * 2 + 1];
        const float w = exp2f((m - M) * LOG2E);
        L += l * w;
        const f32x4 o = *(const f32x4*)(pO + srow * 64 + d4);
        acc += o * w;
    }
    const float invL = (L > 0.f) ? (1.0f / L) : 0.f;
    const f32x4 bv = *(const f32x4*)(bias + d4);
    *(f32x4*)(outp + row * 64 + d4) = acc * invL + bv;
}

// ---------------------------------------------------------------------------
extern "C" void kernel_launch(void* const* d_in, const int* in_sizes, int n_in,
                              void* d_out, int out_size, void* d_ws, size_t ws_size,
                              hipStream_t stream) {
    const float*  x     = (const float*)d_in[0];   // [8,4096,64]
    const int*    graph = (const int*)d_in[1];     // [4096,4096]
    const float*  W     = (const float*)d_in[2];   // [64,64]
    const float*  bias  = (const float*)d_in[3];   // [64]
    float*        outp  = (float*)d_out;

    char* ws = (char*)d_ws;
    _Float16* hptr  = (_Float16*)ws;                         // 4 MiB
    uint32_t* mwptr = (uint32_t*)(ws + (4u << 20));          // 2 MiB

    // choose split count by available workspace: 6 + 8.25*ks MiB needed
    int ks = 1;
    if      (ws_size >= ((size_t)40 << 20)) ks = 4;
    else if (ws_size >= ((size_t)23 << 20)) ks = 2;

    float* pO  = (float*)(ws + (8u << 20));
    float* pml = (float*)(ws + (8u << 20) + (size_t)ks * (8u << 20));

    hproj_kernel<<<dim3(kB * kN / 64), dim3(256), 0, stream>>>(x, W, hptr);
    bitpack_kernel<<<dim3(kN * (kN / 32) / 256), dim3(256), 0, stream>>>(graph, mwptr);

    if (ks == 1) {
        attn_kernel<<<dim3(kN / 64, kB, 1), dim3(256), 0, stream>>>(
            hptr, mwptr, bias, outp, nullptr, nullptr, kN);
    } else {
        attn_kernel<<<dim3(kN / 64, kB, ks), dim3(256), 0, stream>>>(
            hptr, mwptr, bias, nullptr, pO, pml, kN / ks);
        combine_kernel<<<dim3(kB * kN * 16 / 256), dim3(256), 0, stream>>>(
            pO, pml, bias, outp, ks);
    }
}

// Round 5
// 106.030 us; speedup vs baseline: 1.8415x; 1.5710x over previous
//
#include <hip/hip_runtime.h>
#include <stdint.h>

typedef _Float16 f16x8 __attribute__((ext_vector_type(8)));
typedef __fp16 half2_t __attribute__((ext_vector_type(2)));
typedef float f32x4 __attribute__((ext_vector_type(4)));

#define LOG2E 1.44269504088896340736f
#define NEGINF (-1e16f)

constexpr int kN = 4096;   // nodes
constexpr int kD = 64;     // feature dim
constexpr int kB = 8;      // batch

// ---------------------------------------------------------------------------
// Kernel 1: h[row][d] = sum_c x[row][c] * W[d][c]   (f32 math, f16 store)
// ---------------------------------------------------------------------------
__global__ __launch_bounds__(256) void hproj_kernel(const float* __restrict__ x,
                                                    const float* __restrict__ W,
                                                    _Float16* __restrict__ hout)
{
    __shared__ float Wt[64][64];   // Wt[c][d] = W[d][c]
    __shared__ float xs[64][65];

    const int tid = threadIdx.x;
    const int r   = tid >> 2;          // 0..63
    const int c0  = (tid & 3) * 16;    // 0,16,32,48

    #pragma unroll
    for (int j = 0; j < 16; j += 4) {
        const float4 v = *(const float4*)(W + r * 64 + c0 + j);
        Wt[c0 + j + 0][r] = v.x;
        Wt[c0 + j + 1][r] = v.y;
        Wt[c0 + j + 2][r] = v.z;
        Wt[c0 + j + 3][r] = v.w;
    }
    const long rowbase = (long)blockIdx.x * 64;
    #pragma unroll
    for (int j = 0; j < 16; j += 4) {
        const float4 v = *(const float4*)(x + (rowbase + r) * 64 + c0 + j);
        xs[r][c0 + j + 0] = v.x;
        xs[r][c0 + j + 1] = v.y;
        xs[r][c0 + j + 2] = v.z;
        xs[r][c0 + j + 3] = v.w;
    }
    __syncthreads();

    const int d0 = (tid & 3) * 16;
    f32x4 acc[4] = {{0.f,0.f,0.f,0.f},{0.f,0.f,0.f,0.f},{0.f,0.f,0.f,0.f},{0.f,0.f,0.f,0.f}};
    #pragma unroll 4
    for (int c = 0; c < 64; ++c) {
        const float xv = xs[r][c];
        const f32x4* wrow = (const f32x4*)&Wt[c][d0];
        #pragma unroll
        for (int k = 0; k < 4; ++k) acc[k] += wrow[k] * xv;
    }
    f16x8 o0, o1;
    #pragma unroll
    for (int j = 0; j < 8; ++j) {
        o0[j] = (_Float16)acc[j >> 2][j & 3];
        o1[j] = (_Float16)acc[2 + (j >> 2)][j & 3];
    }
    *(f16x8*)(hout + (rowbase + r) * 64 + d0)     = o0;
    *(f16x8*)(hout + (rowbase + r) * 64 + d0 + 8) = o1;
}

// ---------------------------------------------------------------------------
// Kernel 2: bit-pack graph (int32 0/1, [4096][4096]) -> uint32 [4096][128]
// ---------------------------------------------------------------------------
__global__ __launch_bounds__(256) void bitpack_kernel(const int* __restrict__ g,
                                                      uint32_t* __restrict__ mw)
{
    const long w = (long)blockIdx.x * 256 + threadIdx.x;  // word index
    const int4* p = (const int4*)(g + w * 32);
    uint32_t bits = 0;
    #pragma unroll
    for (int j = 0; j < 8; ++j) {
        const int4 v = p[j];
        bits |= (uint32_t)(v.x != 0) << (j * 4 + 0);
        bits |= (uint32_t)(v.y != 0) << (j * 4 + 1);
        bits |= (uint32_t)(v.z != 0) << (j * 4 + 2);
        bits |= (uint32_t)(v.w != 0) << (j * 4 + 3);
    }
    mw[w] = bits;
}

// ---------------------------------------------------------------------------
// Kernel 3: swapped-operand flash attention over a KV chunk.
// grid (64, 8, KS), 256 thr (4 waves); wave handles 16 q rows; KV tiles of 64.
// S^T = mfma(K, Q): lane holds 16 S values for ONE q (= lane&15).
// K LDS rows are bit-permuted so lane's kv slots == PV B-fragment slots:
// P never leaves registers (8 cvt_pkrtz, zero shuffles, zero LDS).
// Mask applied as select-to-NEGINF BEFORE the max (masked-max semantics:
// largest unmasked p == 1, so f16 P never underflows to all-zero rows).
// ---------------------------------------------------------------------------
__global__ __launch_bounds__(256) void attn_kernel(const _Float16* __restrict__ h,
                                                   const uint32_t* __restrict__ mw,
                                                   const float* __restrict__ bias,
                                                   float* __restrict__ outp,
                                                   float* __restrict__ pO,
                                                   float* __restrict__ pml,
                                                   int kvlen)
{
    __shared__ alignas(16) char Kl[2][64 * 128];
    __shared__ alignas(16) char Vt[2][64 * 128];

    const int b     = blockIdx.y;
    const int split = blockIdx.z;
    const int q0    = blockIdx.x * 64;
    const int tid   = threadIdx.x;
    const int wave  = tid >> 6;
    const int lane  = tid & 63;
    const int lg    = lane >> 4;   // 0..3
    const int ll    = lane & 15;   // 0..15

    const _Float16* hb = h + (long)b * kN * kD;
    const int kv_base  = split * kvlen;
    const int NT       = kvlen / 64;

    // Q fragment (B-operand: lane holds Q[q=ll][c=8*lg+e]), resident
    const int q    = q0 + wave * 16 + ll;
    const f16x8 qf0 = *(const f16x8*)(hb + q * 64 + lg * 8);
    const f16x8 qf1 = *(const f16x8*)(hb + q * 64 + 32 + lg * 8);

    // O^T accumulators: lane holds O^T[d = 16*dt + 4*lg + rr][q]
    f32x4 Oacc[4] = {{0.f,0.f,0.f,0.f},{0.f,0.f,0.f,0.f},{0.f,0.f,0.f,0.f},{0.f,0.f,0.f,0.f}};
    float m_run = NEGINF, l_run = 0.f;

    // staging mapping: thread loads global KV row (kv_base + it*64 + sr), cols sc..sc+15
    const int sr = tid >> 2;          // 0..63
    const int sc = (tid & 3) * 16;
    // K rows stored permuted: global kv row sr -> LDS row srp so that
    // QK^T D-row (t,lg,rr) corresponds to kv = 32*(t>>1) + 8*lg + 4*(t&1) + rr
    const int srp = (sr & 0x23) | ((sr & 0x18) >> 1) | ((sr & 0x4) << 2);
    const int swzK = (srp & 7) << 4;

    const uint32_t* mrow_ptr = mw + (long)q * 128 + (kv_base >> 5);

    // ---- stage tile 0 into buf 0 ----
    {
        const _Float16* src = hb + (long)(kv_base + sr) * 64 + sc;
        const f16x8 v0 = *(const f16x8*)(src);
        const f16x8 v1 = *(const f16x8*)(src + 8);
        *(f16x8*)(Kl[0] + srp * 128 + ((sc * 2)      ^ swzK)) = v0;
        *(f16x8*)(Kl[0] + srp * 128 + ((sc * 2 + 16) ^ swzK)) = v1;
        #pragma unroll
        for (int j = 0; j < 8; ++j) {
            const int d1 = sc + j;
            const int d2 = sc + 8 + j;
            *(_Float16*)(Vt[0] + d1 * 128 + ((sr * 2) ^ ((d1 & 7) << 4) ^ ((d1 >> 4) << 5))) = v0[j];
            *(_Float16*)(Vt[0] + d2 * 128 + ((sr * 2) ^ ((d2 & 7) << 4) ^ ((d2 >> 4) << 5))) = v1[j];
        }
    }

    const half2_t one2 = {(__fp16)1.0f, (__fp16)1.0f};

    for (int ith = 0; ith < NT; ith += 2) {
        #pragma unroll
        for (int hh = 0; hh < 2; ++hh) {
            const int it  = ith + hh;
            const int cur = hh;            // buffer parity == it parity

            // ---- early-issue next tile's global loads + this tile's mask ----
            f16x8 nv0{}, nv1{};
            if (it + 1 < NT) {
                const _Float16* src = hb + (long)(kv_base + (it + 1) * 64 + sr) * 64 + sc;
                nv0 = *(const f16x8*)(src);
                nv1 = *(const f16x8*)(src + 8);
            }
            const uint2 mword = *(const uint2*)(mrow_ptr + it * 2);
            const uint32_t u0 = mword.x >> (lg * 8);
            const uint32_t u1 = mword.y >> (lg * 8);

            __syncthreads();   // buf[cur] staged; buf[cur^1] free

            // ---- S^T = K Q^T : lane q=ll, slots (t,rr): kv = 32*(t>>1)+8*lg+4*(t&1)+rr
            f32x4 S[4];
            #pragma unroll
            for (int t = 0; t < 4; ++t) {
                const int krow = t * 16 + ll;
                const char* kb = Kl[cur] + krow * 128;
                const int swz = (krow & 7) << 4;
                const f16x8 k0 = *(const f16x8*)(kb + ((lg * 16)      ^ swz));
                const f16x8 k1 = *(const f16x8*)(kb + ((64 + lg * 16) ^ swz));
                f32x4 s = {0.f, 0.f, 0.f, 0.f};
                s = __builtin_amdgcn_mfma_f32_16x16x32_f16(k0, qf0, s, 0, 0, 0);
                s = __builtin_amdgcn_mfma_f32_16x16x32_f16(k1, qf1, s, 0, 0, 0);
                S[t] = s;
            }

            // ---- mask: select to NEGINF (masked-max semantics, round-2-proven) ----
            #pragma unroll
            for (int t = 0; t < 4; ++t) {
                const uint32_t u = (t < 2) ? u0 : u1;
                #pragma unroll
                for (int rr = 0; rr < 4; ++rr) {
                    const int pos = 4 * (t & 1) + rr;
                    S[t][rr] = ((u >> pos) & 1u) ? S[t][rr] : NEGINF;
                }
            }

            // ---- online softmax, fully lane-local + 2 shuffles ----
            float mx0 = fmaxf(fmaxf(S[0][0], S[0][1]), fmaxf(S[0][2], S[0][3]));
            float mx1 = fmaxf(fmaxf(S[1][0], S[1][1]), fmaxf(S[1][2], S[1][3]));
            float mx2 = fmaxf(fmaxf(S[2][0], S[2][1]), fmaxf(S[2][2], S[2][3]));
            float mx3 = fmaxf(fmaxf(S[3][0], S[3][1]), fmaxf(S[3][2], S[3][3]));
            float mloc = fmaxf(fmaxf(mx0, mx1), fmaxf(mx2, mx3));
            mloc = fmaxf(mloc, __shfl_xor(mloc, 16));
            mloc = fmaxf(mloc, __shfl_xor(mloc, 32));

            const float mnew = fmaxf(m_run, mloc);
            const float scl  = __builtin_amdgcn_exp2f((m_run - mnew) * LOG2E);
            const float mm   = mnew * LOG2E;
            m_run = mnew;

            // exp (masked entries are NEGINF -> exp2(-huge) == 0)
            #pragma unroll
            for (int t = 0; t < 4; ++t) {
                #pragma unroll
                for (int rr = 0; rr < 4; ++rr) {
                    S[t][rr] = __builtin_amdgcn_exp2f(fmaf(S[t][rr], LOG2E, -mm));
                }
            }

            // pack P to f16 fragments (kv slot order == B-fragment order)
            half2_t w0 = __builtin_amdgcn_cvt_pkrtz(S[0][0], S[0][1]);
            half2_t w1 = __builtin_amdgcn_cvt_pkrtz(S[0][2], S[0][3]);
            half2_t w2 = __builtin_amdgcn_cvt_pkrtz(S[1][0], S[1][1]);
            half2_t w3 = __builtin_amdgcn_cvt_pkrtz(S[1][2], S[1][3]);
            half2_t w4 = __builtin_amdgcn_cvt_pkrtz(S[2][0], S[2][1]);
            half2_t w5 = __builtin_amdgcn_cvt_pkrtz(S[2][2], S[2][3]);
            half2_t w6 = __builtin_amdgcn_cvt_pkrtz(S[3][0], S[3][1]);
            half2_t w7 = __builtin_amdgcn_cvt_pkrtz(S[3][2], S[3][3]);

            // tile row-sum from the same (masked, f16-rounded) values as PV
            float lt = 0.f;
            lt = __builtin_amdgcn_fdot2(w0, one2, lt, false);
            lt = __builtin_amdgcn_fdot2(w1, one2, lt, false);
            lt = __builtin_amdgcn_fdot2(w2, one2, lt, false);
            lt = __builtin_amdgcn_fdot2(w3, one2, lt, false);
            lt = __builtin_amdgcn_fdot2(w4, one2, lt, false);
            lt = __builtin_amdgcn_fdot2(w5, one2, lt, false);
            lt = __builtin_amdgcn_fdot2(w6, one2, lt, false);
            lt = __builtin_amdgcn_fdot2(w7, one2, lt, false);
            lt += __shfl_xor(lt, 16);
            lt += __shfl_xor(lt, 32);
            l_run = fmaf(l_run, scl, lt);

            union PF { half2_t h[4]; f16x8 v; };
            PF pf1, pf2;
            pf1.h[0] = w0; pf1.h[1] = w1; pf1.h[2] = w2; pf1.h[3] = w3;
            pf2.h[0] = w4; pf2.h[1] = w5; pf2.h[2] = w6; pf2.h[3] = w7;

            // rescale O^T
            #pragma unroll
            for (int dt = 0; dt < 4; ++dt)
                #pragma unroll
                for (int rr = 0; rr < 4; ++rr)
                    Oacc[dt][rr] *= scl;

            // ---- O^T += V^T P^T ----
            #pragma unroll
            for (int dt = 0; dt < 4; ++dt) {
                const int vrow = dt * 16 + ll;
                const char* vb = Vt[cur] + vrow * 128;
                const int swz = ((vrow & 7) << 4) ^ (dt << 5);
                const f16x8 v0 = *(const f16x8*)(vb + ((lg * 16)      ^ swz));
                const f16x8 v1 = *(const f16x8*)(vb + ((64 + lg * 16) ^ swz));
                Oacc[dt] = __builtin_amdgcn_mfma_f32_16x16x32_f16(v0, pf1.v, Oacc[dt], 0, 0, 0);
                Oacc[dt] = __builtin_amdgcn_mfma_f32_16x16x32_f16(v1, pf2.v, Oacc[dt], 0, 0, 0);
            }

            // ---- write prefetched tile into the other buffer ----
            if (it + 1 < NT) {
                const int nb = cur ^ 1;
                *(f16x8*)(Kl[nb] + srp * 128 + ((sc * 2)      ^ swzK)) = nv0;
                *(f16x8*)(Kl[nb] + srp * 128 + ((sc * 2 + 16) ^ swzK)) = nv1;
                #pragma unroll
                for (int j = 0; j < 8; ++j) {
                    const int d1 = sc + j;
                    const int d2 = sc + 8 + j;
                    *(_Float16*)(Vt[nb] + d1 * 128 + ((sr * 2) ^ ((d1 & 7) << 4) ^ ((d1 >> 4) << 5))) = nv0[j];
                    *(_Float16*)(Vt[nb] + d2 * 128 + ((sr * 2) ^ ((d2 & 7) << 4) ^ ((d2 >> 4) << 5))) = nv1[j];
                }
            }
        }
    }

    // ---- epilogue: lane owns q = ll-row, d = 16*dt + 4*lg + rr ----
    if (outp != nullptr) {
        const float inv = 1.0f / l_run;
        #pragma unroll
        for (int dt = 0; dt < 4; ++dt) {
            const int dbase = dt * 16 + lg * 4;
            const f32x4 bv = *(const f32x4*)(bias + dbase);
            f32x4 o;
            #pragma unroll
            for (int rr = 0; rr < 4; ++rr) o[rr] = Oacc[dt][rr] * inv + bv[rr];
            *(f32x4*)(outp + ((long)b * kN + q) * 64 + dbase) = o;
        }
    } else {
        const long srow = (long)split * kB * kN + (long)b * kN + q;
        #pragma unroll
        for (int dt = 0; dt < 4; ++dt) {
            const int dbase = dt * 16 + lg * 4;
            *(f32x4*)(pO + srow * 64 + dbase) = Oacc[dt];
        }
        if (lane < 16) {
            pml[srow * 2 + 0] = m_run;
            pml[srow * 2 + 1] = l_run;
        }
    }
}

// ---------------------------------------------------------------------------
// Kernel 4: combine split-KV partials.
// ---------------------------------------------------------------------------
__global__ __launch_bounds__(256) void combine_kernel(const float* __restrict__ pO,
                                                      const float* __restrict__ pml,
                                                      const float* __restrict__ bias,
                                                      float* __restrict__ outp,
                                                      int ks)
{
    const long idx = (long)blockIdx.x * 256 + threadIdx.x;  // B*N*16 groups
    const long row = idx >> 4;
    const int  d4  = (int)(idx & 15) * 4;

    float M = NEGINF;
    for (int s = 0; s < ks; ++s)
        M = fmaxf(M, pml[((long)s * kB * kN + row) * 2]);

    float L = 0.f;
    f32x4 acc = {0.f, 0.f, 0.f, 0.f};
    for (int s = 0; s < ks; ++s) {
        const long srow = (long)s * kB * kN + row;
        const float m = pml[srow * 2 + 0];
        const float l = pml[srow * 2 + 1];
        const float w = __builtin_amdgcn_exp2f((m - M) * LOG2E);
        L += l * w;
        const f32x4 o = *(const f32x4*)(pO + srow * 64 + d4);
        acc += o * w;
    }
    const float invL = (L > 0.f) ? (1.0f / L) : 0.f;
    const f32x4 bv = *(const f32x4*)(bias + d4);
    *(f32x4*)(outp + row * 64 + d4) = acc * invL + bv;
}

// ---------------------------------------------------------------------------
extern "C" void kernel_launch(void* const* d_in, const int* in_sizes, int n_in,
                              void* d_out, int out_size, void* d_ws, size_t ws_size,
                              hipStream_t stream) {
    const float*  x     = (const float*)d_in[0];   // [8,4096,64]
    const int*    graph = (const int*)d_in[1];     // [4096,4096]
    const float*  W     = (const float*)d_in[2];   // [64,64]
    const float*  bias  = (const float*)d_in[3];   // [64]
    float*        outp  = (float*)d_out;

    char* ws = (char*)d_ws;
    _Float16* hptr  = (_Float16*)ws;                         // 4 MiB
    uint32_t* mwptr = (uint32_t*)(ws + (4u << 20));          // 2 MiB

    int ks = 1;
    if      (ws_size >= ((size_t)42 << 20)) ks = 4;
    else if (ws_size >= ((size_t)25 << 20)) ks = 2;

    float* pO  = (float*)(ws + (8u << 20));
    float* pml = (float*)(ws + (8u << 20) + (size_t)ks * (8u << 20));

    hproj_kernel<<<dim3(kB * kN / 64), dim3(256), 0, stream>>>(x, W, hptr);
    bitpack_kernel<<<dim3(kN * (kN / 32) / 256), dim3(256), 0, stream>>>(graph, mwptr);

    if (ks == 1) {
        attn_kernel<<<dim3(kN / 64, kB, 1), dim3(256), 0, stream>>>(
            hptr, mwptr, bias, outp, nullptr, nullptr, kN);
    } else {
        attn_kernel<<<dim3(kN / 64, kB, ks), dim3(256), 0, stream>>>(
            hptr, mwptr, bias, nullptr, pO, pml, kN / ks);
        combine_kernel<<<dim3(kB * kN * 16 / 256), dim3(256), 0, stream>>>(
            pO, pml, bias, outp, ks);
    }
}